// Round 2
// baseline (1209.398 us; speedup 1.0000x reference)
//
#include <hip/hip_runtime.h>
#include <hip/hip_bf16.h>

#define C_  64
#define C3_ 192
#define T_  10
#define H_  128
#define W_  128
#define HW_ 16384        // H_*W_
#define THW_ 163840      // T_*HW_
#define NH_ 8
#define C2_ 24
#define TG_ 80           // t * SHUFFLE_G

typedef __hip_bfloat16 bf16;

__device__ __forceinline__ float bf2f(bf16 v) { return __bfloat162float(v); }

__device__ __forceinline__ void unpack8(uint4 u, float* f) {
  f[0] = __uint_as_float(u.x << 16); f[1] = __uint_as_float(u.x & 0xffff0000u);
  f[2] = __uint_as_float(u.y << 16); f[3] = __uint_as_float(u.y & 0xffff0000u);
  f[4] = __uint_as_float(u.z << 16); f[5] = __uint_as_float(u.z & 0xffff0000u);
  f[6] = __uint_as_float(u.w << 16); f[7] = __uint_as_float(u.w & 0xffff0000u);
}

// ---------------- K1: pointwise conv  y1 = W1 @ x  (one batch) ----------------
// grid: T*HW/256 = 640 blocks; thread = one (t,s)
__global__ __launch_bounds__(256) void k1_pointwise(
    const float* __restrict__ x, const float* __restrict__ W1,
    bf16* __restrict__ y1) {
  int p = blockIdx.x * 256 + threadIdx.x;       // t*HW + s
  int s = p & (HW_ - 1);
  int t = p >> 14;
  const float* xp = x + (size_t)t * HW_ + s;
  float xr[C_];
#pragma unroll
  for (int c = 0; c < C_; ++c) xr[c] = xp[(size_t)c * THW_];
  bf16* yp = y1 + (size_t)t * HW_ + s;
  for (int o = 0; o < C3_; ++o) {
    float acc = 0.f;
#pragma unroll
    for (int c = 0; c < C_; ++c) acc = fmaf(W1[o * C_ + c], xr[c], acc);
    yp[(size_t)o * THW_] = __float2bfloat16(acc);
  }
}

// ---------------- K2: depthwise 3x3 (spatial), zero pad (one batch) ----------------
// blockIdx.x = (o*T + t)*16 + strip ; strip covers 8 rows
__global__ __launch_bounds__(256) void k2_dw(
    const bf16* __restrict__ y1, const float* __restrict__ Wdw,
    bf16* __restrict__ y2) {
  __shared__ float tile[10][132];   // rows hs-1..hs+8, cols -1..128
  int blk = blockIdx.x;
  int hs = (blk & 15) * 8;
  int rest = blk >> 4;
  int t = rest % T_;
  int o = rest / T_;
  const bf16* src = y1 + ((size_t)o * T_ + t) * HW_;
  for (int idx = threadIdx.x; idx < 10 * 130; idx += 256) {
    int r = idx / 130, cc = idx % 130;
    int hh = hs - 1 + r, ww = cc - 1;
    float v = 0.f;
    if (hh >= 0 && hh < H_ && ww >= 0 && ww < W_)
      v = bf2f(src[hh * W_ + ww]);
    tile[r][cc] = v;
  }
  __syncthreads();
  float kk[9];
#pragma unroll
  for (int i = 0; i < 9; ++i) kk[i] = Wdw[o * 9 + i];
  bf16* dst = y2 + ((size_t)o * T_ + t) * HW_;
  int r = threadIdx.x >> 5;            // 0..7
  int w0 = (threadIdx.x & 31) * 4;     // 0..124
#pragma unroll
  for (int dw = 0; dw < 4; ++dw) {
    int ww = w0 + dw;
    float acc = 0.f;
#pragma unroll
    for (int ky = 0; ky < 3; ++ky)
#pragma unroll
      for (int kx = 0; kx < 3; ++kx)
        acc = fmaf(kk[ky * 3 + kx], tile[r + ky][ww + kx], acc);
    dst[(hs + r) * W_ + ww] = __float2bfloat16(acc);
  }
}

// ---------------- K3: shuffle + 80x80 linear + unshuffle -> z (one batch) ----------------
// z layout: (u = c2*80 + o, hw), u in [0,1920)
// input i = c1*10+t  <->  y2 channel c1*24+c2 at time t
// grid: C2*HW/256 = 1536 blocks; thread = (c2, s)
__global__ __launch_bounds__(256) void k3_linear(
    const bf16* __restrict__ y2, const float* __restrict__ W_lin,
    const float* __restrict__ b_lin, bf16* __restrict__ z) {
  int gp = blockIdx.x * 256 + threadIdx.x;
  int s = gp & (HW_ - 1);
  int c2 = gp >> 14;
  float in[TG_];
#pragma unroll
  for (int c1 = 0; c1 < 8; ++c1) {
    const bf16* p = y2 + (size_t)(c1 * C2_ + c2) * THW_ + s;
#pragma unroll
    for (int t = 0; t < T_; ++t) in[c1 * T_ + t] = bf2f(p[(size_t)t * HW_]);
  }
  bf16* zp = z + (size_t)(c2 * TG_) * HW_ + s;
  for (int o = 0; o < TG_; ++o) {
    float acc = b_lin[o];
#pragma unroll
    for (int i = 0; i < TG_; ++i) acc = fmaf(W_lin[o * TG_ + i], in[i], acc);
    zp[(size_t)o * HW_] = __float2bfloat16(acc);
  }
}

// ---------------- K4: sum of squares for q,k rows (one batch) ----------------
// grid: 1280 blocks (u in [0,1280)), 256 threads
__global__ __launch_bounds__(256) void k4_ssq(
    const bf16* __restrict__ z, float* __restrict__ ssq) {
  __shared__ float red[256];
  int u = blockIdx.x;
  const bf16* p = z + (size_t)u * HW_;
  float acc = 0.f;
  for (int it = 0; it < 8; ++it) {
    int s = it * 2048 + threadIdx.x * 8;
    uint4 raw = *reinterpret_cast<const uint4*>(p + s);
    float f[8]; unpack8(raw, f);
#pragma unroll
    for (int e = 0; e < 8; ++e) acc = fmaf(f[e], f[e], acc);
  }
  red[threadIdx.x] = acc;
  __syncthreads();
  for (int st = 128; st > 0; st >>= 1) {
    if (threadIdx.x < st) red[threadIdx.x] += red[threadIdx.x + st];
    __syncthreads();
  }
  if (threadIdx.x == 0) ssq[u] = red[0];
}

// ---------------- K5: QK^T partial sums over s-chunks (one batch) ----------------
// grid: 8 heads * 32 chunks = 256 blocks; 256 threads as 16x16, 5x5 reg tile
__global__ __launch_bounds__(256) void k5_qk(
    const bf16* __restrict__ z, float* __restrict__ Gpart) {
  int h = blockIdx.x >> 5, chunk = blockIdx.x & 31;
  int ti = threadIdx.x >> 4, tj = threadIdx.x & 15;
  const bf16* qbase = z + (size_t)(h * TG_) * HW_;
  const bf16* kbase = z + (size_t)((8 + h) * TG_) * HW_;
  float acc[5][5] = {};
  int s0 = chunk * 512;
  for (int s = s0; s < s0 + 512; s += 8) {
    uint4 qraw[5], kraw[5];
#pragma unroll
    for (int a = 0; a < 5; ++a)
      qraw[a] = *reinterpret_cast<const uint4*>(qbase + (size_t)(ti + 16 * a) * HW_ + s);
#pragma unroll
    for (int a = 0; a < 5; ++a)
      kraw[a] = *reinterpret_cast<const uint4*>(kbase + (size_t)(tj + 16 * a) * HW_ + s);
    float qf[5][8], kf[5][8];
#pragma unroll
    for (int a = 0; a < 5; ++a) unpack8(qraw[a], qf[a]);
#pragma unroll
    for (int a = 0; a < 5; ++a) unpack8(kraw[a], kf[a]);
#pragma unroll
    for (int a = 0; a < 5; ++a)
#pragma unroll
      for (int b2 = 0; b2 < 5; ++b2)
#pragma unroll
        for (int e = 0; e < 8; ++e)
          acc[a][b2] = fmaf(qf[a][e], kf[b2][e], acc[a][b2]);
  }
#pragma unroll
  for (int a = 0; a < 5; ++a)
#pragma unroll
    for (int b2 = 0; b2 < 5; ++b2)
      Gpart[(((size_t)chunk * 8 + h) * TG_ + (ti + 16 * a)) * TG_ + (tj + 16 * b2)] =
          acc[a][b2];
}

// ---------------- K6: reduce partials, normalize, temperature, softmax (one batch) ----------------
// grid: 8*80 = 640 blocks (h, i); 128 threads, j = tid
__global__ __launch_bounds__(128) void k6_softmax(
    const float* __restrict__ Gpart, const float* __restrict__ ssq,
    const float* __restrict__ temp, float* __restrict__ attn) {
  __shared__ float red[128];
  __shared__ float smax, ssum;
  int h = blockIdx.x / TG_, i = blockIdx.x % TG_;
  int j = threadIdx.x;
  float logit = -1e30f;
  if (j < TG_) {
    float g = 0.f;
    for (int c = 0; c < 32; ++c)
      g += Gpart[(((size_t)c * 8 + h) * TG_ + i) * TG_ + j];
    float nq = ssq[h * TG_ + i];
    float nk = ssq[(8 + h) * TG_ + j];
    float sq = 1.f / fmaxf(sqrtf(nq), 1e-12f);
    float sk = 1.f / fmaxf(sqrtf(nk), 1e-12f);
    logit = g * sq * sk * temp[h];
  }
  red[j] = logit;
  __syncthreads();
  if (j == 0) {
    float m = -1e30f;
    for (int x2 = 0; x2 < TG_; ++x2) m = fmaxf(m, red[x2]);
    smax = m;
  }
  __syncthreads();
  float e = (j < TG_) ? expf(logit - smax) : 0.f;
  red[j] = e;
  __syncthreads();
  if (j == 0) {
    float s = 0.f;
    for (int x2 = 0; x2 < TG_; ++x2) s += red[x2];
    ssum = s;
  }
  __syncthreads();
  if (j < TG_) attn[((size_t)h * TG_ + i) * TG_ + j] = e / ssum;
}

// ---------------- K7a: att_out = attn @ v (one batch) ----------------
// grid: 8 heads * 64 s-chunks = 512 blocks; thread = one s
__global__ __launch_bounds__(256) void k7a_pv(
    const bf16* __restrict__ z, const float* __restrict__ attn,
    bf16* __restrict__ att_out) {
  int h = blockIdx.x >> 6, sc = blockIdx.x & 63;
  int s = sc * 256 + threadIdx.x;
  const bf16* vbase = z + (size_t)((16 + h) * TG_) * HW_ + s;
  float vr[TG_];
#pragma unroll
  for (int e = 0; e < TG_; ++e) vr[e] = bf2f(vbase[(size_t)e * HW_]);
  const float* ap = attn + (size_t)h * TG_ * TG_;
  bf16* op = att_out + (size_t)(h * TG_) * HW_ + s;
  for (int ct = 0; ct < TG_; ++ct) {
    float acc = 0.f;
#pragma unroll
    for (int e = 0; e < TG_; ++e) acc = fmaf(ap[ct * TG_ + e], vr[e], acc);
    op[(size_t)ct * HW_] = __float2bfloat16(acc);
  }
}

// ---------------- K7b: out = W_out @ att_out (channel regroup, one batch) ----------------
// grid: T*HW/256 = 640 blocks; thread = (t,s)
__global__ __launch_bounds__(256) void k7b_wout(
    const bf16* __restrict__ att_out, const float* __restrict__ W_out,
    float* __restrict__ out) {
  int p = blockIdx.x * 256 + threadIdx.x;
  int s = p & (HW_ - 1);
  int t = p >> 14;
  float ir[C_];
#pragma unroll
  for (int c = 0; c < C_; ++c) {
    int h = c >> 3, c1 = c & 7;
    ir[c] = bf2f(att_out[(size_t)(h * TG_ + c1 * T_ + t) * HW_ + s]);
  }
  float* op = out + (size_t)t * HW_ + s;
  for (int o = 0; o < C_; ++o) {
    float acc = 0.f;
#pragma unroll
    for (int c = 0; c < C_; ++c) acc = fmaf(W_out[o * C_ + c], ir[c], acc);
    op[(size_t)o * THW_] = acc;
  }
}

extern "C" void kernel_launch(void* const* d_in, const int* in_sizes, int n_in,
                              void* d_out, int out_size, void* d_ws, size_t ws_size,
                              hipStream_t stream) {
  const float* x    = (const float*)d_in[0];
  const float* W1   = (const float*)d_in[1];
  const float* Wdw  = (const float*)d_in[2];
  const float* Wlin = (const float*)d_in[3];
  const float* blin = (const float*)d_in[4];
  const float* temp = (const float*)d_in[5];
  const float* Wout = (const float*)d_in[6];
  float* out = (float*)d_out;

  // Per-batch workspace: two 60 MB slots, reused across stages.
  // slotA: y1 -> z (K3 reads only y2)    slotB: y2 -> {Gpart, attn, ssq, att_out}
  const size_t SLOT = (size_t)C3_ * THW_ * 2;   // 62,914,560 bytes
  char* ws = (char*)d_ws;
  bf16* slotA = (bf16*)ws;
  char* slotB = ws + SLOT;

  bf16* y1 = slotA;
  bf16* y2 = (bf16*)slotB;
  bf16* z  = slotA;                              // overwrites y1 (dead after K2)
  float* Gpart   = (float*)slotB;                // 32*8*80*80*4 = 6,553,600 B
  float* attn    = (float*)(slotB + 6553600);    // 8*80*80*4    =   204,800 B
  float* ssq     = (float*)(slotB + 6758400);    // 1280*4       =     5,120 B
  bf16*  att_out = (bf16*)(slotB + 6763520);     // 8*80*16384*2 = 20,971,520 B

  for (int b = 0; b < 2; ++b) {
    const float* x_b = x + (size_t)b * C_ * THW_;
    float* out_b = out + (size_t)b * C_ * THW_;

    k1_pointwise<<<(T_ * HW_) / 256, 256, 0, stream>>>(x_b, W1, y1);
    k2_dw<<<C3_ * T_ * 16, 256, 0, stream>>>(y1, Wdw, y2);
    k3_linear<<<(C2_ * HW_) / 256, 256, 0, stream>>>(y2, Wlin, blin, z);
    k4_ssq<<<1280, 256, 0, stream>>>(z, ssq);
    k5_qk<<<8 * 32, 256, 0, stream>>>(z, Gpart);
    k6_softmax<<<8 * TG_, 128, 0, stream>>>(Gpart, ssq, temp, attn);
    k7a_pv<<<8 * 64, 256, 0, stream>>>(z, attn, att_out);
    k7b_wout<<<(T_ * HW_) / 256, 256, 0, stream>>>(att_out, Wout, out_b);
  }
}

// Round 3
// 685.272 us; speedup vs baseline: 1.7648x; 1.7648x over previous
//
#include <hip/hip_runtime.h>
#include <hip/hip_bf16.h>

#define C_  64
#define C3_ 192
#define T_  10
#define H_  128
#define W_  128
#define HW_ 16384        // H_*W_
#define THW_ 163840      // T_*HW_
#define NH_ 8
#define C2_ 24
#define TG_ 80           // t * SHUFFLE_G

typedef __hip_bfloat16 bf16;
typedef __attribute__((ext_vector_type(8))) short bf16x8;
typedef __attribute__((ext_vector_type(4))) float f32x4;

__device__ __forceinline__ float bf2f(bf16 v) { return __bfloat162float(v); }

__device__ __forceinline__ short f2bf_s(float f) {
  bf16 h = __float2bfloat16(f);
  union { bf16 b; short s; } u; u.b = h; return u.s;
}

__device__ __forceinline__ void unpack8(uint4 u, float* f) {
  f[0] = __uint_as_float(u.x << 16); f[1] = __uint_as_float(u.x & 0xffff0000u);
  f[2] = __uint_as_float(u.y << 16); f[3] = __uint_as_float(u.y & 0xffff0000u);
  f[4] = __uint_as_float(u.z << 16); f[5] = __uint_as_float(u.z & 0xffff0000u);
  f[6] = __uint_as_float(u.w << 16); f[7] = __uint_as_float(u.w & 0xffff0000u);
}

// ================ K1 (MFMA): y1[o][n] = W1[o][c] @ x[c][n],  K=64, M=192(split 2x96), N=163840 ================
// LDS: X stripe [64 k][256 cols] stored col-major in 16B chunks, rotated: phys = (kc+col)%10
#define K1_NKC 10
#define K1_STRIDE 160   // bytes per col = 10 chunks * 16B
__global__ __launch_bounds__(256) void k1_mfma(
    const float* __restrict__ x, const float* __restrict__ W1,
    bf16* __restrict__ y1) {
  __shared__ __align__(16) char lds[256 * K1_STRIDE];   // 40 KiB
  const int tid = threadIdx.x;
  const int n0 = blockIdx.x * 256;
  const int mh = blockIdx.y;            // m-half: 0 or 1 (96 rows each)

  // ---- stage x[64][n0..n0+256) -> LDS (f32 -> bf16) ----
  {
    const int cg = tid >> 3, dk = tid & 7;        // colgroup 0..31, k-offset 0..7
    for (int it = 0; it < 8; ++it) {
      const int k = it * 8 + dk;                  // 0..63
      const float* src = x + (size_t)k * THW_ + n0 + cg * 8;
      float4 f0 = *reinterpret_cast<const float4*>(src);
      float4 f1 = *reinterpret_cast<const float4*>(src + 4);
      short v[8];
      v[0]=f2bf_s(f0.x); v[1]=f2bf_s(f0.y); v[2]=f2bf_s(f0.z); v[3]=f2bf_s(f0.w);
      v[4]=f2bf_s(f1.x); v[5]=f2bf_s(f1.y); v[6]=f2bf_s(f1.z); v[7]=f2bf_s(f1.w);
      const int kc = k >> 3, ke = k & 7;
      int r = (kc + cg * 8) % K1_NKC;
#pragma unroll
      for (int j = 0; j < 8; ++j) {
        const int col = cg * 8 + j;
        *reinterpret_cast<short*>(lds + col * K1_STRIDE + r * 16 + ke * 2) = v[j];
        r = (r + 1 == K1_NKC) ? 0 : r + 1;
      }
    }
  }
  __syncthreads();

  const int lane = tid & 63, wv = tid >> 6;
  const int lr = lane & 15, lg = lane >> 4;

  // ---- A fragments: W1 rows [mh*96 .. +96), 6 m-tiles x 2 k-chunks ----
  bf16x8 wf[6][2];
#pragma unroll
  for (int mt = 0; mt < 6; ++mt)
#pragma unroll
    for (int c = 0; c < 2; ++c) {
      const int row = mh * 96 + mt * 16 + lr;
      const int k0 = c * 32 + lg * 8;
      const float* wp = W1 + row * 64 + k0;
      float4 a0 = *reinterpret_cast<const float4*>(wp);
      float4 a1 = *reinterpret_cast<const float4*>(wp + 4);
      bf16x8 f;
      f[0]=f2bf_s(a0.x); f[1]=f2bf_s(a0.y); f[2]=f2bf_s(a0.z); f[3]=f2bf_s(a0.w);
      f[4]=f2bf_s(a1.x); f[5]=f2bf_s(a1.y); f[6]=f2bf_s(a1.z); f[7]=f2bf_s(a1.w);
      wf[mt][c] = f;
    }

  // ---- compute: 4 n-tiles per wave ----
  for (int nt = 0; nt < 4; ++nt) {
    const int col = wv * 64 + nt * 16 + lr;
    f32x4 acc[6];
#pragma unroll
    for (int mt = 0; mt < 6; ++mt) acc[mt] = (f32x4){0.f, 0.f, 0.f, 0.f};
#pragma unroll
    for (int c = 0; c < 2; ++c) {
      const int kc = c * 4 + lg;
      const bf16x8 b = *reinterpret_cast<const bf16x8*>(
          lds + col * K1_STRIDE + ((kc + col) % K1_NKC) * 16);
#pragma unroll
      for (int mt = 0; mt < 6; ++mt)
        acc[mt] = __builtin_amdgcn_mfma_f32_16x16x32_bf16(wf[mt][c], b, acc[mt], 0, 0, 0);
    }
#pragma unroll
    for (int mt = 0; mt < 6; ++mt)
#pragma unroll
      for (int j = 0; j < 4; ++j) {
        const int o = mh * 96 + mt * 16 + lg * 4 + j;
        y1[(size_t)o * THW_ + n0 + col] = __float2bfloat16(acc[mt][j]);
      }
  }
}

// ================ K2: depthwise 3x3 (spatial), zero pad (one batch) — unchanged ================
__global__ __launch_bounds__(256) void k2_dw(
    const bf16* __restrict__ y1, const float* __restrict__ Wdw,
    bf16* __restrict__ y2) {
  __shared__ float tile[10][132];
  int blk = blockIdx.x;
  int hs = (blk & 15) * 8;
  int rest = blk >> 4;
  int t = rest % T_;
  int o = rest / T_;
  const bf16* src = y1 + ((size_t)o * T_ + t) * HW_;
  for (int idx = threadIdx.x; idx < 10 * 130; idx += 256) {
    int r = idx / 130, cc = idx % 130;
    int hh = hs - 1 + r, ww = cc - 1;
    float v = 0.f;
    if (hh >= 0 && hh < H_ && ww >= 0 && ww < W_)
      v = bf2f(src[hh * W_ + ww]);
    tile[r][cc] = v;
  }
  __syncthreads();
  float kk[9];
#pragma unroll
  for (int i = 0; i < 9; ++i) kk[i] = Wdw[o * 9 + i];
  bf16* dst = y2 + ((size_t)o * T_ + t) * HW_;
  int r = threadIdx.x >> 5;
  int w0 = (threadIdx.x & 31) * 4;
#pragma unroll
  for (int dw = 0; dw < 4; ++dw) {
    int ww = w0 + dw;
    float acc = 0.f;
#pragma unroll
    for (int ky = 0; ky < 3; ++ky)
#pragma unroll
      for (int kx = 0; kx < 3; ++kx)
        acc = fmaf(kk[ky * 3 + kx], tile[r + ky][ww + kx], acc);
    dst[(hs + r) * W_ + ww] = __float2bfloat16(acc);
  }
}

// ================ K3 (MFMA): z[c2*80+o][s] = W_lin[o][i] @ X[i][s] + b,  K=80(pad 96), M=80 ================
// X[i][s] = y2[(c1*24+c2)*10+t][s], i = c1*10+t.  LDS rotated col-major, NKC=14.
#define K3_NKC 14
#define K3_STRIDE 224   // bytes per col = 14 chunks * 16B
__global__ __launch_bounds__(256) void k3_mfma(
    const bf16* __restrict__ y2, const float* __restrict__ W_lin,
    const float* __restrict__ b_lin, bf16* __restrict__ z) {
  __shared__ __align__(16) char lds[256 * K3_STRIDE];   // 56 KiB
  const int tid = threadIdx.x;
  const int s0 = blockIdx.x * 256;
  const int c2 = blockIdx.y;

  // ---- stage X[80][s0..s0+256) -> LDS ----
  {
    const int cg = tid >> 3, dk = tid & 7;
    for (int it = 0; it < 10; ++it) {
      const int k = it * 8 + dk;                  // i = 0..79
      const int c1 = (k * 205) >> 11;             // k/10
      const int tt = k - c1 * 10;
      const bf16* src = y2 + ((size_t)((c1 * C2_ + c2) * T_ + tt)) * HW_ + s0 + cg * 8;
      uint4 raw = *reinterpret_cast<const uint4*>(src);
      const ushort* v = reinterpret_cast<const ushort*>(&raw);
      const int kc = k >> 3, ke = k & 7;
      int r = (kc + cg * 8) % K3_NKC;
#pragma unroll
      for (int j = 0; j < 8; ++j) {
        const int col = cg * 8 + j;
        *reinterpret_cast<ushort*>(lds + col * K3_STRIDE + r * 16 + ke * 2) = v[j];
        r = (r + 1 == K3_NKC) ? 0 : r + 1;
      }
    }
    // zero logical chunks 10,11 (k = 80..95)
    const int col = tid;
    const uint4 zero4 = {0, 0, 0, 0};
    *reinterpret_cast<uint4*>(lds + col * K3_STRIDE + ((10 + col) % K3_NKC) * 16) = zero4;
    *reinterpret_cast<uint4*>(lds + col * K3_STRIDE + ((11 + col) % K3_NKC) * 16) = zero4;
  }
  __syncthreads();

  const int lane = tid & 63, wv = tid >> 6;
  const int lr = lane & 15, lg = lane >> 4;

  // ---- A fragments: W_lin (80x80, pad K to 96), 5 m-tiles x 3 k-chunks ----
  bf16x8 wf[5][3];
#pragma unroll
  for (int mt = 0; mt < 5; ++mt)
#pragma unroll
    for (int c = 0; c < 3; ++c) {
      const int row = mt * 16 + lr;
      const int k0 = c * 32 + lg * 8;
      bf16x8 f;
      if (k0 < 80) {
        const float* wp = W_lin + row * 80 + k0;
        float4 a0 = *reinterpret_cast<const float4*>(wp);
        float4 a1 = *reinterpret_cast<const float4*>(wp + 4);
        f[0]=f2bf_s(a0.x); f[1]=f2bf_s(a0.y); f[2]=f2bf_s(a0.z); f[3]=f2bf_s(a0.w);
        f[4]=f2bf_s(a1.x); f[5]=f2bf_s(a1.y); f[6]=f2bf_s(a1.z); f[7]=f2bf_s(a1.w);
      } else {
        f = (bf16x8){0,0,0,0,0,0,0,0};
      }
      wf[mt][c] = f;
    }
  // bias per accumulator slot
  float bias[5][4];
#pragma unroll
  for (int mt = 0; mt < 5; ++mt)
#pragma unroll
    for (int j = 0; j < 4; ++j) bias[mt][j] = b_lin[mt * 16 + lg * 4 + j];

  // ---- compute: 4 n-tiles per wave ----
  for (int nt = 0; nt < 4; ++nt) {
    const int col = wv * 64 + nt * 16 + lr;
    f32x4 acc[5];
#pragma unroll
    for (int mt = 0; mt < 5; ++mt)
      acc[mt] = (f32x4){bias[mt][0], bias[mt][1], bias[mt][2], bias[mt][3]};
#pragma unroll
    for (int c = 0; c < 3; ++c) {
      const int kc = c * 4 + lg;
      const bf16x8 b = *reinterpret_cast<const bf16x8*>(
          lds + col * K3_STRIDE + ((kc + col) % K3_NKC) * 16);
#pragma unroll
      for (int mt = 0; mt < 5; ++mt)
        acc[mt] = __builtin_amdgcn_mfma_f32_16x16x32_bf16(wf[mt][c], b, acc[mt], 0, 0, 0);
    }
#pragma unroll
    for (int mt = 0; mt < 5; ++mt)
#pragma unroll
      for (int j = 0; j < 4; ++j) {
        const int u = c2 * TG_ + mt * 16 + lg * 4 + j;
        z[(size_t)u * HW_ + s0 + col] = __float2bfloat16(acc[mt][j]);
      }
  }
}

// ================ K4: sum of squares for q,k rows — unchanged ================
__global__ __launch_bounds__(256) void k4_ssq(
    const bf16* __restrict__ z, float* __restrict__ ssq) {
  __shared__ float red[256];
  int u = blockIdx.x;
  const bf16* p = z + (size_t)u * HW_;
  float acc = 0.f;
  for (int it = 0; it < 8; ++it) {
    int s = it * 2048 + threadIdx.x * 8;
    uint4 raw = *reinterpret_cast<const uint4*>(p + s);
    float f[8]; unpack8(raw, f);
#pragma unroll
    for (int e = 0; e < 8; ++e) acc = fmaf(f[e], f[e], acc);
  }
  red[threadIdx.x] = acc;
  __syncthreads();
  for (int st = 128; st > 0; st >>= 1) {
    if (threadIdx.x < st) red[threadIdx.x] += red[threadIdx.x + st];
    __syncthreads();
  }
  if (threadIdx.x == 0) ssq[u] = red[0];
}

// ================ K5: QK^T partial sums — unchanged ================
__global__ __launch_bounds__(256) void k5_qk(
    const bf16* __restrict__ z, float* __restrict__ Gpart) {
  int h = blockIdx.x >> 5, chunk = blockIdx.x & 31;
  int ti = threadIdx.x >> 4, tj = threadIdx.x & 15;
  const bf16* qbase = z + (size_t)(h * TG_) * HW_;
  const bf16* kbase = z + (size_t)((8 + h) * TG_) * HW_;
  float acc[5][5] = {};
  int s0 = chunk * 512;
  for (int s = s0; s < s0 + 512; s += 8) {
    uint4 qraw[5], kraw[5];
#pragma unroll
    for (int a = 0; a < 5; ++a)
      qraw[a] = *reinterpret_cast<const uint4*>(qbase + (size_t)(ti + 16 * a) * HW_ + s);
#pragma unroll
    for (int a = 0; a < 5; ++a)
      kraw[a] = *reinterpret_cast<const uint4*>(kbase + (size_t)(tj + 16 * a) * HW_ + s);
    float qf[5][8], kf[5][8];
#pragma unroll
    for (int a = 0; a < 5; ++a) unpack8(qraw[a], qf[a]);
#pragma unroll
    for (int a = 0; a < 5; ++a) unpack8(kraw[a], kf[a]);
#pragma unroll
    for (int a = 0; a < 5; ++a)
#pragma unroll
      for (int b2 = 0; b2 < 5; ++b2)
#pragma unroll
        for (int e = 0; e < 8; ++e)
          acc[a][b2] = fmaf(qf[a][e], kf[b2][e], acc[a][b2]);
  }
#pragma unroll
  for (int a = 0; a < 5; ++a)
#pragma unroll
    for (int b2 = 0; b2 < 5; ++b2)
      Gpart[(((size_t)chunk * 8 + h) * TG_ + (ti + 16 * a)) * TG_ + (tj + 16 * b2)] =
          acc[a][b2];
}

// ================ K6: softmax — unchanged ================
__global__ __launch_bounds__(128) void k6_softmax(
    const float* __restrict__ Gpart, const float* __restrict__ ssq,
    const float* __restrict__ temp, float* __restrict__ attn) {
  __shared__ float red[128];
  __shared__ float smax, ssum;
  int h = blockIdx.x / TG_, i = blockIdx.x % TG_;
  int j = threadIdx.x;
  float logit = -1e30f;
  if (j < TG_) {
    float g = 0.f;
    for (int c = 0; c < 32; ++c)
      g += Gpart[(((size_t)c * 8 + h) * TG_ + i) * TG_ + j];
    float nq = ssq[h * TG_ + i];
    float nk = ssq[(8 + h) * TG_ + j];
    float sq = 1.f / fmaxf(sqrtf(nq), 1e-12f);
    float sk = 1.f / fmaxf(sqrtf(nk), 1e-12f);
    logit = g * sq * sk * temp[h];
  }
  red[j] = logit;
  __syncthreads();
  if (j == 0) {
    float m = -1e30f;
    for (int x2 = 0; x2 < TG_; ++x2) m = fmaxf(m, red[x2]);
    smax = m;
  }
  __syncthreads();
  float e = (j < TG_) ? expf(logit - smax) : 0.f;
  red[j] = e;
  __syncthreads();
  if (j == 0) {
    float s = 0.f;
    for (int x2 = 0; x2 < TG_; ++x2) s += red[x2];
    ssum = s;
  }
  __syncthreads();
  if (j < TG_) attn[((size_t)h * TG_ + i) * TG_ + j] = e / ssum;
}

// ================ K7a: att_out = attn @ v — unchanged ================
__global__ __launch_bounds__(256) void k7a_pv(
    const bf16* __restrict__ z, const float* __restrict__ attn,
    bf16* __restrict__ att_out) {
  int h = blockIdx.x >> 6, sc = blockIdx.x & 63;
  int s = sc * 256 + threadIdx.x;
  const bf16* vbase = z + (size_t)((16 + h) * TG_) * HW_ + s;
  float vr[TG_];
#pragma unroll
  for (int e = 0; e < TG_; ++e) vr[e] = bf2f(vbase[(size_t)e * HW_]);
  const float* ap = attn + (size_t)h * TG_ * TG_;
  bf16* op = att_out + (size_t)(h * TG_) * HW_ + s;
  for (int ct = 0; ct < TG_; ++ct) {
    float acc = 0.f;
#pragma unroll
    for (int e = 0; e < TG_; ++e) acc = fmaf(ap[ct * TG_ + e], vr[e], acc);
    op[(size_t)ct * HW_] = __float2bfloat16(acc);
  }
}

// ================ K7b: out = W_out @ att_out — unchanged ================
__global__ __launch_bounds__(256) void k7b_wout(
    const bf16* __restrict__ att_out, const float* __restrict__ W_out,
    float* __restrict__ out) {
  int p = blockIdx.x * 256 + threadIdx.x;
  int s = p & (HW_ - 1);
  int t = p >> 14;
  float ir[C_];
#pragma unroll
  for (int c = 0; c < C_; ++c) {
    int h = c >> 3, c1 = c & 7;
    ir[c] = bf2f(att_out[(size_t)(h * TG_ + c1 * T_ + t) * HW_ + s]);
  }
  float* op = out + (size_t)t * HW_ + s;
  for (int o = 0; o < C_; ++o) {
    float acc = 0.f;
#pragma unroll
    for (int c = 0; c < C_; ++c) acc = fmaf(W_out[o * C_ + c], ir[c], acc);
    op[(size_t)o * THW_] = acc;
  }
}

extern "C" void kernel_launch(void* const* d_in, const int* in_sizes, int n_in,
                              void* d_out, int out_size, void* d_ws, size_t ws_size,
                              hipStream_t stream) {
  const float* x    = (const float*)d_in[0];
  const float* W1   = (const float*)d_in[1];
  const float* Wdw  = (const float*)d_in[2];
  const float* Wlin = (const float*)d_in[3];
  const float* blin = (const float*)d_in[4];
  const float* temp = (const float*)d_in[5];
  const float* Wout = (const float*)d_in[6];
  float* out = (float*)d_out;

  // Per-batch workspace: two 60 MB slots, reused across stages.
  const size_t SLOT = (size_t)C3_ * THW_ * 2;   // 62,914,560 bytes
  char* ws = (char*)d_ws;
  bf16* slotA = (bf16*)ws;
  char* slotB = ws + SLOT;

  bf16* y1 = slotA;
  bf16* y2 = (bf16*)slotB;
  bf16* z  = slotA;                              // overwrites y1 (dead after K2)
  float* Gpart   = (float*)slotB;                // 6,553,600 B
  float* attn    = (float*)(slotB + 6553600);    //   204,800 B
  float* ssq     = (float*)(slotB + 6758400);    //     5,120 B
  bf16*  att_out = (bf16*)(slotB + 6763520);     // 20,971,520 B

  for (int b = 0; b < 2; ++b) {
    const float* x_b = x + (size_t)b * C_ * THW_;
    float* out_b = out + (size_t)b * C_ * THW_;

    k1_mfma<<<dim3(THW_ / 256, 2), 256, 0, stream>>>(x_b, W1, y1);
    k2_dw<<<C3_ * T_ * 16, 256, 0, stream>>>(y1, Wdw, y2);
    k3_mfma<<<dim3(HW_ / 256, C2_), 256, 0, stream>>>(y2, Wlin, blin, z);
    k4_ssq<<<1280, 256, 0, stream>>>(z, ssq);
    k5_qk<<<8 * 32, 256, 0, stream>>>(z, Gpart);
    k6_softmax<<<8 * TG_, 128, 0, stream>>>(Gpart, ssq, temp, attn);
    k7a_pv<<<8 * 64, 256, 0, stream>>>(z, attn, att_out);
    k7b_wout<<<(T_ * HW_) / 256, 256, 0, stream>>>(att_out, Wout, out_b);
  }
}

// Round 4
// 365.659 us; speedup vs baseline: 3.3074x; 1.8741x over previous
//
#include <hip/hip_runtime.h>
#include <hip/hip_bf16.h>

#define C_  64
#define C3_ 192
#define T_  10
#define H_  128
#define W_  128
#define HW_ 16384        // H_*W_
#define THW_ 163840      // T_*HW_
#define NH_ 8
#define C2_ 24
#define TG_ 80           // t * SHUFFLE_G

typedef __hip_bfloat16 bf16;
typedef __attribute__((ext_vector_type(8))) short bf16x8;
typedef __attribute__((ext_vector_type(4))) float f32x4;

__device__ __forceinline__ float bf2f(bf16 v) { return __bfloat162float(v); }

__device__ __forceinline__ short f2bf_s(float f) {
  bf16 h = __float2bfloat16(f);
  union { bf16 b; short s; } u; u.b = h; return u.s;
}

__device__ __forceinline__ void unpack8(uint4 u, float* f) {
  f[0] = __uint_as_float(u.x << 16); f[1] = __uint_as_float(u.x & 0xffff0000u);
  f[2] = __uint_as_float(u.y << 16); f[3] = __uint_as_float(u.y & 0xffff0000u);
  f[4] = __uint_as_float(u.z << 16); f[5] = __uint_as_float(u.z & 0xffff0000u);
  f[6] = __uint_as_float(u.w << 16); f[7] = __uint_as_float(u.w & 0xffff0000u);
}

// ================ K1 (MFMA): y1[o][n] = W1[o][c] @ x[c][n],  K=64, M=192(split 2x96) ================
#define K1_NKC 10
#define K1_STRIDE 160   // bytes per col = 10 chunks * 16B
__global__ __launch_bounds__(256) void k1_mfma(
    const float* __restrict__ x, const float* __restrict__ W1,
    bf16* __restrict__ y1) {
  __shared__ __align__(16) char lds[256 * K1_STRIDE];   // 40 KiB
  const int tid = threadIdx.x;
  const int n0 = blockIdx.x * 256;
  const int mh = blockIdx.y;

  {
    const int cg = tid >> 3, dk = tid & 7;
    for (int it = 0; it < 8; ++it) {
      const int k = it * 8 + dk;
      const float* src = x + (size_t)k * THW_ + n0 + cg * 8;
      float4 f0 = *reinterpret_cast<const float4*>(src);
      float4 f1 = *reinterpret_cast<const float4*>(src + 4);
      short v[8];
      v[0]=f2bf_s(f0.x); v[1]=f2bf_s(f0.y); v[2]=f2bf_s(f0.z); v[3]=f2bf_s(f0.w);
      v[4]=f2bf_s(f1.x); v[5]=f2bf_s(f1.y); v[6]=f2bf_s(f1.z); v[7]=f2bf_s(f1.w);
      const int kc = k >> 3, ke = k & 7;
      int r = (kc + cg * 8) % K1_NKC;
#pragma unroll
      for (int j = 0; j < 8; ++j) {
        const int col = cg * 8 + j;
        *reinterpret_cast<short*>(lds + col * K1_STRIDE + r * 16 + ke * 2) = v[j];
        r = (r + 1 == K1_NKC) ? 0 : r + 1;
      }
    }
  }
  __syncthreads();

  const int lane = tid & 63, wv = tid >> 6;
  const int lr = lane & 15, lg = lane >> 4;

  bf16x8 wf[6][2];
#pragma unroll
  for (int mt = 0; mt < 6; ++mt)
#pragma unroll
    for (int c = 0; c < 2; ++c) {
      const int row = mh * 96 + mt * 16 + lr;
      const int k0 = c * 32 + lg * 8;
      const float* wp = W1 + row * 64 + k0;
      float4 a0 = *reinterpret_cast<const float4*>(wp);
      float4 a1 = *reinterpret_cast<const float4*>(wp + 4);
      bf16x8 f;
      f[0]=f2bf_s(a0.x); f[1]=f2bf_s(a0.y); f[2]=f2bf_s(a0.z); f[3]=f2bf_s(a0.w);
      f[4]=f2bf_s(a1.x); f[5]=f2bf_s(a1.y); f[6]=f2bf_s(a1.z); f[7]=f2bf_s(a1.w);
      wf[mt][c] = f;
    }

  for (int nt = 0; nt < 4; ++nt) {
    const int col = wv * 64 + nt * 16 + lr;
    f32x4 acc[6];
#pragma unroll
    for (int mt = 0; mt < 6; ++mt) acc[mt] = (f32x4){0.f, 0.f, 0.f, 0.f};
#pragma unroll
    for (int c = 0; c < 2; ++c) {
      const int kc = c * 4 + lg;
      const bf16x8 b = *reinterpret_cast<const bf16x8*>(
          lds + col * K1_STRIDE + ((kc + col) % K1_NKC) * 16);
#pragma unroll
      for (int mt = 0; mt < 6; ++mt)
        acc[mt] = __builtin_amdgcn_mfma_f32_16x16x32_bf16(wf[mt][c], b, acc[mt], 0, 0, 0);
    }
#pragma unroll
    for (int mt = 0; mt < 6; ++mt)
#pragma unroll
      for (int j = 0; j < 4; ++j) {
        const int o = mh * 96 + mt * 16 + lg * 4 + j;
        y1[(size_t)o * THW_ + n0 + col] = __float2bfloat16(acc[mt][j]);
      }
  }
}

// ================ K2: depthwise 3x3 (spatial), zero pad — unchanged ================
__global__ __launch_bounds__(256) void k2_dw(
    const bf16* __restrict__ y1, const float* __restrict__ Wdw,
    bf16* __restrict__ y2) {
  __shared__ float tile[10][132];
  int blk = blockIdx.x;
  int hs = (blk & 15) * 8;
  int rest = blk >> 4;
  int t = rest % T_;
  int o = rest / T_;
  const bf16* src = y1 + ((size_t)o * T_ + t) * HW_;
  for (int idx = threadIdx.x; idx < 10 * 130; idx += 256) {
    int r = idx / 130, cc = idx % 130;
    int hh = hs - 1 + r, ww = cc - 1;
    float v = 0.f;
    if (hh >= 0 && hh < H_ && ww >= 0 && ww < W_)
      v = bf2f(src[hh * W_ + ww]);
    tile[r][cc] = v;
  }
  __syncthreads();
  float kk[9];
#pragma unroll
  for (int i = 0; i < 9; ++i) kk[i] = Wdw[o * 9 + i];
  bf16* dst = y2 + ((size_t)o * T_ + t) * HW_;
  int r = threadIdx.x >> 5;
  int w0 = (threadIdx.x & 31) * 4;
#pragma unroll
  for (int dw = 0; dw < 4; ++dw) {
    int ww = w0 + dw;
    float acc = 0.f;
#pragma unroll
    for (int ky = 0; ky < 3; ++ky)
#pragma unroll
      for (int kx = 0; kx < 3; ++kx)
        acc = fmaf(kk[ky * 3 + kx], tile[r + ky][ww + kx], acc);
    dst[(hs + r) * W_ + ww] = __float2bfloat16(acc);
  }
}

// ================ K3 (MFMA): z = W_lin @ shuffled(y2) + b,  K=80(pad 96), M=80 ================
#define K3_NKC 14
#define K3_STRIDE 224
__global__ __launch_bounds__(256) void k3_mfma(
    const bf16* __restrict__ y2, const float* __restrict__ W_lin,
    const float* __restrict__ b_lin, bf16* __restrict__ z) {
  __shared__ __align__(16) char lds[256 * K3_STRIDE];   // 56 KiB
  const int tid = threadIdx.x;
  const int s0 = blockIdx.x * 256;
  const int c2 = blockIdx.y;

  {
    const int cg = tid >> 3, dk = tid & 7;
    for (int it = 0; it < 10; ++it) {
      const int k = it * 8 + dk;
      const int c1 = (k * 205) >> 11;
      const int tt = k - c1 * 10;
      const bf16* src = y2 + ((size_t)((c1 * C2_ + c2) * T_ + tt)) * HW_ + s0 + cg * 8;
      uint4 raw = *reinterpret_cast<const uint4*>(src);
      const ushort* v = reinterpret_cast<const ushort*>(&raw);
      const int kc = k >> 3, ke = k & 7;
      int r = (kc + cg * 8) % K3_NKC;
#pragma unroll
      for (int j = 0; j < 8; ++j) {
        const int col = cg * 8 + j;
        *reinterpret_cast<ushort*>(lds + col * K3_STRIDE + r * 16 + ke * 2) = v[j];
        r = (r + 1 == K3_NKC) ? 0 : r + 1;
      }
    }
    const int col = tid;
    const uint4 zero4 = {0, 0, 0, 0};
    *reinterpret_cast<uint4*>(lds + col * K3_STRIDE + ((10 + col) % K3_NKC) * 16) = zero4;
    *reinterpret_cast<uint4*>(lds + col * K3_STRIDE + ((11 + col) % K3_NKC) * 16) = zero4;
  }
  __syncthreads();

  const int lane = tid & 63, wv = tid >> 6;
  const int lr = lane & 15, lg = lane >> 4;

  bf16x8 wf[5][3];
#pragma unroll
  for (int mt = 0; mt < 5; ++mt)
#pragma unroll
    for (int c = 0; c < 3; ++c) {
      const int row = mt * 16 + lr;
      const int k0 = c * 32 + lg * 8;
      bf16x8 f;
      if (k0 < 80) {
        const float* wp = W_lin + row * 80 + k0;
        float4 a0 = *reinterpret_cast<const float4*>(wp);
        float4 a1 = *reinterpret_cast<const float4*>(wp + 4);
        f[0]=f2bf_s(a0.x); f[1]=f2bf_s(a0.y); f[2]=f2bf_s(a0.z); f[3]=f2bf_s(a0.w);
        f[4]=f2bf_s(a1.x); f[5]=f2bf_s(a1.y); f[6]=f2bf_s(a1.z); f[7]=f2bf_s(a1.w);
      } else {
        f = (bf16x8){0,0,0,0,0,0,0,0};
      }
      wf[mt][c] = f;
    }
  float bias[5][4];
#pragma unroll
  for (int mt = 0; mt < 5; ++mt)
#pragma unroll
    for (int j = 0; j < 4; ++j) bias[mt][j] = b_lin[mt * 16 + lg * 4 + j];

  for (int nt = 0; nt < 4; ++nt) {
    const int col = wv * 64 + nt * 16 + lr;
    f32x4 acc[5];
#pragma unroll
    for (int mt = 0; mt < 5; ++mt)
      acc[mt] = (f32x4){bias[mt][0], bias[mt][1], bias[mt][2], bias[mt][3]};
#pragma unroll
    for (int c = 0; c < 3; ++c) {
      const int kc = c * 4 + lg;
      const bf16x8 b = *reinterpret_cast<const bf16x8*>(
          lds + col * K3_STRIDE + ((kc + col) % K3_NKC) * 16);
#pragma unroll
      for (int mt = 0; mt < 5; ++mt)
        acc[mt] = __builtin_amdgcn_mfma_f32_16x16x32_bf16(wf[mt][c], b, acc[mt], 0, 0, 0);
    }
#pragma unroll
    for (int mt = 0; mt < 5; ++mt)
#pragma unroll
      for (int j = 0; j < 4; ++j) {
        const int u = c2 * TG_ + mt * 16 + lg * 4 + j;
        z[(size_t)u * HW_ + s0 + col] = __float2bfloat16(acc[mt][j]);
      }
  }
}

// ================ K4: sum of squares for q,k rows — unchanged ================
__global__ __launch_bounds__(256) void k4_ssq(
    const bf16* __restrict__ z, float* __restrict__ ssq) {
  __shared__ float red[256];
  int u = blockIdx.x;
  const bf16* p = z + (size_t)u * HW_;
  float acc = 0.f;
  for (int it = 0; it < 8; ++it) {
    int s = it * 2048 + threadIdx.x * 8;
    uint4 raw = *reinterpret_cast<const uint4*>(p + s);
    float f[8]; unpack8(raw, f);
#pragma unroll
    for (int e = 0; e < 8; ++e) acc = fmaf(f[e], f[e], acc);
  }
  red[threadIdx.x] = acc;
  __syncthreads();
  for (int st = 128; st > 0; st >>= 1) {
    if (threadIdx.x < st) red[threadIdx.x] += red[threadIdx.x + st];
    __syncthreads();
  }
  if (threadIdx.x == 0) ssq[u] = red[0];
}

// ================ K5 (MFMA): Gpart[chunk] = partial QK^T over 512-s chunk ================
// grid: (32 chunks, 8 heads), 256 thr = 4 waves, each wave a 128-s strip; LDS tree-reduce.
__global__ __launch_bounds__(256) void k5_mfma(
    const bf16* __restrict__ z, float* __restrict__ Gpart) {
  __shared__ __align__(16) float gbuf[2][TG_ * TG_];   // 51.2 KiB
  const int chunk = blockIdx.x, h = blockIdx.y;
  const int tid = threadIdx.x;
  const int lane = tid & 63, wv = tid >> 6;
  const int lr = lane & 15, lg = lane >> 4;

  const bf16* qbase = z + (size_t)(h * TG_) * HW_;
  const bf16* kbase = z + (size_t)((8 + h) * TG_) * HW_;

  f32x4 acc[5][5];
#pragma unroll
  for (int a = 0; a < 5; ++a)
#pragma unroll
    for (int b2 = 0; b2 < 5; ++b2) acc[a][b2] = (f32x4){0.f, 0.f, 0.f, 0.f};

  const int s0 = chunk * 512 + wv * 128;
  for (int s = s0; s < s0 + 128; s += 32) {
    bf16x8 qa[5], kb[5];
#pragma unroll
    for (int a = 0; a < 5; ++a)
      qa[a] = *reinterpret_cast<const bf16x8*>(qbase + (size_t)(a * 16 + lr) * HW_ + s + lg * 8);
#pragma unroll
    for (int a = 0; a < 5; ++a)
      kb[a] = *reinterpret_cast<const bf16x8*>(kbase + (size_t)(a * 16 + lr) * HW_ + s + lg * 8);
#pragma unroll
    for (int a = 0; a < 5; ++a)
#pragma unroll
      for (int b2 = 0; b2 < 5; ++b2)
        acc[a][b2] = __builtin_amdgcn_mfma_f32_16x16x32_bf16(qa[a], kb[b2], acc[a][b2], 0, 0, 0);
  }

  // tree-reduce the 4 waves' partial G
  if (wv == 1 || wv == 3) {
    float* dst = gbuf[wv >> 1];
#pragma unroll
    for (int a = 0; a < 5; ++a)
#pragma unroll
      for (int b2 = 0; b2 < 5; ++b2)
#pragma unroll
        for (int j = 0; j < 4; ++j)
          dst[(a * 16 + lg * 4 + j) * TG_ + b2 * 16 + lr] = acc[a][b2][j];
  }
  __syncthreads();
  if (wv == 0 || wv == 2) {
    const float* srcb = gbuf[wv >> 1];
#pragma unroll
    for (int a = 0; a < 5; ++a)
#pragma unroll
      for (int b2 = 0; b2 < 5; ++b2)
#pragma unroll
        for (int j = 0; j < 4; ++j)
          acc[a][b2][j] += srcb[(a * 16 + lg * 4 + j) * TG_ + b2 * 16 + lr];
  }
  __syncthreads();
  if (wv == 2) {
#pragma unroll
    for (int a = 0; a < 5; ++a)
#pragma unroll
      for (int b2 = 0; b2 < 5; ++b2)
#pragma unroll
        for (int j = 0; j < 4; ++j)
          gbuf[0][(a * 16 + lg * 4 + j) * TG_ + b2 * 16 + lr] = acc[a][b2][j];
  }
  __syncthreads();
  if (wv == 0) {
    float* gp = Gpart + ((size_t)chunk * 8 + h) * TG_ * TG_;
#pragma unroll
    for (int a = 0; a < 5; ++a)
#pragma unroll
      for (int b2 = 0; b2 < 5; ++b2)
#pragma unroll
        for (int j = 0; j < 4; ++j) {
          const int i = a * 16 + lg * 4 + j, jj = b2 * 16 + lr;
          gp[i * TG_ + jj] = acc[a][b2][j] + gbuf[0][i * TG_ + jj];
        }
  }
}

// ================ K6: softmax — unchanged ================
__global__ __launch_bounds__(128) void k6_softmax(
    const float* __restrict__ Gpart, const float* __restrict__ ssq,
    const float* __restrict__ temp, float* __restrict__ attn) {
  __shared__ float red[128];
  __shared__ float smax, ssum;
  int h = blockIdx.x / TG_, i = blockIdx.x % TG_;
  int j = threadIdx.x;
  float logit = -1e30f;
  if (j < TG_) {
    float g = 0.f;
    for (int c = 0; c < 32; ++c)
      g += Gpart[(((size_t)c * 8 + h) * TG_ + i) * TG_ + j];
    float nq = ssq[h * TG_ + i];
    float nk = ssq[(8 + h) * TG_ + j];
    float sq = 1.f / fmaxf(sqrtf(nq), 1e-12f);
    float sk = 1.f / fmaxf(sqrtf(nk), 1e-12f);
    logit = g * sq * sk * temp[h];
  }
  red[j] = logit;
  __syncthreads();
  if (j == 0) {
    float m = -1e30f;
    for (int x2 = 0; x2 < TG_; ++x2) m = fmaxf(m, red[x2]);
    smax = m;
  }
  __syncthreads();
  float e = (j < TG_) ? expf(logit - smax) : 0.f;
  red[j] = e;
  __syncthreads();
  if (j == 0) {
    float s = 0.f;
    for (int x2 = 0; x2 < TG_; ++x2) s += red[x2];
    ssum = s;
  }
  __syncthreads();
  if (j < TG_) attn[((size_t)h * TG_ + i) * TG_ + j] = e / ssum;
}

// ================ K7a (MFMA): att_out = attn @ v,  M=80, K=80(pad 96), per head ================
__global__ __launch_bounds__(256) void k7a_mfma(
    const bf16* __restrict__ z, const float* __restrict__ attn,
    bf16* __restrict__ att_out) {
  __shared__ __align__(16) char lds[256 * K3_STRIDE];   // 56 KiB
  const int tid = threadIdx.x;
  const int s0 = blockIdx.x * 256;
  const int h = blockIdx.y;
  const int voff = (16 + h) * TG_;

  // ---- stage V[80][s0..s0+256) -> LDS ----
  {
    const int cg = tid >> 3, dk = tid & 7;
    for (int it = 0; it < 10; ++it) {
      const int k = it * 8 + dk;
      const bf16* src = z + (size_t)(voff + k) * HW_ + s0 + cg * 8;
      uint4 raw = *reinterpret_cast<const uint4*>(src);
      const ushort* v = reinterpret_cast<const ushort*>(&raw);
      const int kc = k >> 3, ke = k & 7;
      int r = (kc + cg * 8) % K3_NKC;
#pragma unroll
      for (int j = 0; j < 8; ++j) {
        const int col = cg * 8 + j;
        *reinterpret_cast<ushort*>(lds + col * K3_STRIDE + r * 16 + ke * 2) = v[j];
        r = (r + 1 == K3_NKC) ? 0 : r + 1;
      }
    }
    const int col = tid;
    const uint4 zero4 = {0, 0, 0, 0};
    *reinterpret_cast<uint4*>(lds + col * K3_STRIDE + ((10 + col) % K3_NKC) * 16) = zero4;
    *reinterpret_cast<uint4*>(lds + col * K3_STRIDE + ((11 + col) % K3_NKC) * 16) = zero4;
  }
  __syncthreads();

  const int lane = tid & 63, wv = tid >> 6;
  const int lr = lane & 15, lg = lane >> 4;

  // ---- A fragments from attn[h] (f32 -> bf16), 5 m-tiles x 3 k-chunks ----
  bf16x8 wf[5][3];
#pragma unroll
  for (int mt = 0; mt < 5; ++mt)
#pragma unroll
    for (int c = 0; c < 3; ++c) {
      const int row = mt * 16 + lr;
      const int k0 = c * 32 + lg * 8;
      bf16x8 f;
      if (k0 < 80) {
        const float* ap = attn + ((size_t)h * TG_ + row) * TG_ + k0;
        float4 a0 = *reinterpret_cast<const float4*>(ap);
        float4 a1 = *reinterpret_cast<const float4*>(ap + 4);
        f[0]=f2bf_s(a0.x); f[1]=f2bf_s(a0.y); f[2]=f2bf_s(a0.z); f[3]=f2bf_s(a0.w);
        f[4]=f2bf_s(a1.x); f[5]=f2bf_s(a1.y); f[6]=f2bf_s(a1.z); f[7]=f2bf_s(a1.w);
      } else {
        f = (bf16x8){0,0,0,0,0,0,0,0};
      }
      wf[mt][c] = f;
    }

  for (int nt = 0; nt < 4; ++nt) {
    const int col = wv * 64 + nt * 16 + lr;
    f32x4 acc[5];
#pragma unroll
    for (int mt = 0; mt < 5; ++mt) acc[mt] = (f32x4){0.f, 0.f, 0.f, 0.f};
#pragma unroll
    for (int c = 0; c < 3; ++c) {
      const int kc = c * 4 + lg;
      const bf16x8 b = *reinterpret_cast<const bf16x8*>(
          lds + col * K3_STRIDE + ((kc + col) % K3_NKC) * 16);
#pragma unroll
      for (int mt = 0; mt < 5; ++mt)
        acc[mt] = __builtin_amdgcn_mfma_f32_16x16x32_bf16(wf[mt][c], b, acc[mt], 0, 0, 0);
    }
#pragma unroll
    for (int mt = 0; mt < 5; ++mt)
#pragma unroll
      for (int j = 0; j < 4; ++j) {
        const int u = h * TG_ + mt * 16 + lg * 4 + j;
        att_out[(size_t)u * HW_ + s0 + col] = __float2bfloat16(acc[mt][j]);
      }
  }
}

// ================ K7b (MFMA): out = W_out @ regroup(att_out),  M=64, K=64, f32 out ================
__global__ __launch_bounds__(256) void k7b_mfma(
    const bf16* __restrict__ att_out, const float* __restrict__ W_out,
    float* __restrict__ out) {
  __shared__ __align__(16) char lds[256 * K1_STRIDE];   // 40 KiB
  const int tid = threadIdx.x;
  const int n0 = blockIdx.x * 256;
  const int t = n0 >> 14;                 // constant per block
  const int sb = n0 & (HW_ - 1);

  // ---- stage regrouped att_out rows -> LDS (k -> row (k>>3)*80 + (k&7)*10 + t) ----
  {
    const int cg = tid >> 3, dk = tid & 7;
    for (int it = 0; it < 8; ++it) {
      const int k = it * 8 + dk;
      const int row = (k >> 3) * TG_ + (k & 7) * T_ + t;
      const bf16* src = att_out + (size_t)row * HW_ + sb + cg * 8;
      uint4 raw = *reinterpret_cast<const uint4*>(src);
      const ushort* v = reinterpret_cast<const ushort*>(&raw);
      const int kc = k >> 3, ke = k & 7;
      int r = (kc + cg * 8) % K1_NKC;
#pragma unroll
      for (int j = 0; j < 8; ++j) {
        const int col = cg * 8 + j;
        *reinterpret_cast<ushort*>(lds + col * K1_STRIDE + r * 16 + ke * 2) = v[j];
        r = (r + 1 == K1_NKC) ? 0 : r + 1;
      }
    }
  }
  __syncthreads();

  const int lane = tid & 63, wv = tid >> 6;
  const int lr = lane & 15, lg = lane >> 4;

  bf16x8 wf[4][2];
#pragma unroll
  for (int mt = 0; mt < 4; ++mt)
#pragma unroll
    for (int c = 0; c < 2; ++c) {
      const int row = mt * 16 + lr;
      const int k0 = c * 32 + lg * 8;
      const float* wp = W_out + row * 64 + k0;
      float4 a0 = *reinterpret_cast<const float4*>(wp);
      float4 a1 = *reinterpret_cast<const float4*>(wp + 4);
      bf16x8 f;
      f[0]=f2bf_s(a0.x); f[1]=f2bf_s(a0.y); f[2]=f2bf_s(a0.z); f[3]=f2bf_s(a0.w);
      f[4]=f2bf_s(a1.x); f[5]=f2bf_s(a1.y); f[6]=f2bf_s(a1.z); f[7]=f2bf_s(a1.w);
      wf[mt][c] = f;
    }

  for (int nt = 0; nt < 4; ++nt) {
    const int col = wv * 64 + nt * 16 + lr;
    f32x4 acc[4];
#pragma unroll
    for (int mt = 0; mt < 4; ++mt) acc[mt] = (f32x4){0.f, 0.f, 0.f, 0.f};
#pragma unroll
    for (int c = 0; c < 2; ++c) {
      const int kc = c * 4 + lg;
      const bf16x8 b = *reinterpret_cast<const bf16x8*>(
          lds + col * K1_STRIDE + ((kc + col) % K1_NKC) * 16);
#pragma unroll
      for (int mt = 0; mt < 4; ++mt)
        acc[mt] = __builtin_amdgcn_mfma_f32_16x16x32_bf16(wf[mt][c], b, acc[mt], 0, 0, 0);
    }
#pragma unroll
    for (int mt = 0; mt < 4; ++mt)
#pragma unroll
      for (int j = 0; j < 4; ++j) {
        const int o = mt * 16 + lg * 4 + j;
        out[(size_t)o * THW_ + n0 + col] = acc[mt][j];
      }
  }
}

extern "C" void kernel_launch(void* const* d_in, const int* in_sizes, int n_in,
                              void* d_out, int out_size, void* d_ws, size_t ws_size,
                              hipStream_t stream) {
  const float* x    = (const float*)d_in[0];
  const float* W1   = (const float*)d_in[1];
  const float* Wdw  = (const float*)d_in[2];
  const float* Wlin = (const float*)d_in[3];
  const float* blin = (const float*)d_in[4];
  const float* temp = (const float*)d_in[5];
  const float* Wout = (const float*)d_in[6];
  float* out = (float*)d_out;

  const size_t SLOT = (size_t)C3_ * THW_ * 2;   // 62,914,560 bytes
  char* ws = (char*)d_ws;
  bf16* slotA = (bf16*)ws;
  char* slotB = ws + SLOT;

  bf16* y1 = slotA;
  bf16* y2 = (bf16*)slotB;
  bf16* z  = slotA;
  float* Gpart   = (float*)slotB;                // 6,553,600 B
  float* attn    = (float*)(slotB + 6553600);    //   204,800 B
  float* ssq     = (float*)(slotB + 6758400);    //     5,120 B
  bf16*  att_out = (bf16*)(slotB + 6763520);     // 20,971,520 B

  for (int b = 0; b < 2; ++b) {
    const float* x_b = x + (size_t)b * C_ * THW_;
    float* out_b = out + (size_t)b * C_ * THW_;

    k1_mfma<<<dim3(THW_ / 256, 2), 256, 0, stream>>>(x_b, W1, y1);
    k2_dw<<<C3_ * T_ * 16, 256, 0, stream>>>(y1, Wdw, y2);
    k3_mfma<<<dim3(HW_ / 256, C2_), 256, 0, stream>>>(y2, Wlin, blin, z);
    k4_ssq<<<1280, 256, 0, stream>>>(z, ssq);
    k5_mfma<<<dim3(32, NH_), 256, 0, stream>>>(z, Gpart);
    k6_softmax<<<8 * TG_, 128, 0, stream>>>(Gpart, ssq, temp, attn);
    k7a_mfma<<<dim3(HW_ / 256, NH_), 256, 0, stream>>>(z, attn, att_out);
    k7b_mfma<<<THW_ / 256, 256, 0, stream>>>(att_out, Wout, out_b);
  }
}

// Round 5
// 337.259 us; speedup vs baseline: 3.5860x; 1.0842x over previous
//
#include <hip/hip_runtime.h>
#include <hip/hip_bf16.h>

#define C_  64
#define C3_ 192
#define T_  10
#define H_  128
#define W_  128
#define HW_ 16384        // H_*W_
#define THW_ 163840      // T_*HW_
#define NH_ 8
#define C2_ 24
#define TG_ 80           // t * SHUFFLE_G

typedef __hip_bfloat16 bf16;
typedef __attribute__((ext_vector_type(8))) short bf16x8;
typedef __attribute__((ext_vector_type(4))) float f32x4;

__device__ __forceinline__ float bf2f(bf16 v) { return __bfloat162float(v); }

__device__ __forceinline__ ushort f2bf_s(float f) {
  bf16 h = __float2bfloat16(f);
  union { bf16 b; ushort s; } u; u.b = h; return u.s;
}

__device__ __forceinline__ void unpack8(uint4 u, float* f) {
  f[0] = __uint_as_float(u.x << 16); f[1] = __uint_as_float(u.x & 0xffff0000u);
  f[2] = __uint_as_float(u.y << 16); f[3] = __uint_as_float(u.y & 0xffff0000u);
  f[4] = __uint_as_float(u.z << 16); f[5] = __uint_as_float(u.z & 0xffff0000u);
  f[6] = __uint_as_float(u.w << 16); f[7] = __uint_as_float(u.w & 0xffff0000u);
}

__device__ __forceinline__ ushort4 pack4(f32x4 a) {
  ushort4 p;
  p.x = f2bf_s(a[0]); p.y = f2bf_s(a[1]); p.z = f2bf_s(a[2]); p.w = f2bf_s(a[3]);
  return p;
}

// ================ K1 (MFMA, swapped): y1 = W1 @ x, A = x-frag, B = W-frag ================
#define K1_NKC 10
#define K1_STRIDE 160   // bytes per col = 10 chunks * 16B
__global__ __launch_bounds__(256) void k1_mfma(
    const float* __restrict__ x, const float* __restrict__ W1,
    bf16* __restrict__ y1) {
  __shared__ __align__(16) char lds[256 * K1_STRIDE];   // 40 KiB
  const int tid = threadIdx.x;
  const int n0 = blockIdx.x * 256;
  const int mh = blockIdx.y;

  // ---- stage x[64][n0..n0+256) -> LDS (pre-issue all loads) ----
  {
    const int cg = tid >> 3, dk = tid & 7;
    float4 f0[8], f1[8];
#pragma unroll
    for (int it = 0; it < 8; ++it) {
      const int k = it * 8 + dk;
      const float* src = x + (size_t)k * THW_ + n0 + cg * 8;
      f0[it] = *reinterpret_cast<const float4*>(src);
      f1[it] = *reinterpret_cast<const float4*>(src + 4);
    }
#pragma unroll
    for (int it = 0; it < 8; ++it) {
      ushort v[8];
      v[0]=f2bf_s(f0[it].x); v[1]=f2bf_s(f0[it].y); v[2]=f2bf_s(f0[it].z); v[3]=f2bf_s(f0[it].w);
      v[4]=f2bf_s(f1[it].x); v[5]=f2bf_s(f1[it].y); v[6]=f2bf_s(f1[it].z); v[7]=f2bf_s(f1[it].w);
      int r = (it + cg * 8) % K1_NKC;
#pragma unroll
      for (int j = 0; j < 8; ++j) {
        const int col = cg * 8 + j;
        *reinterpret_cast<ushort*>(lds + col * K1_STRIDE + r * 16 + dk * 2) = v[j];
        r = (r + 1 == K1_NKC) ? 0 : r + 1;
      }
    }
  }
  __syncthreads();

  const int lane = tid & 63, wv = tid >> 6;
  const int lr = lane & 15, lg = lane >> 4;

  // ---- B fragments: W1 rows (o-channels), 6 m-tiles x 2 k-chunks ----
  bf16x8 wf[6][2];
#pragma unroll
  for (int mt = 0; mt < 6; ++mt)
#pragma unroll
    for (int c = 0; c < 2; ++c) {
      const int row = mh * 96 + mt * 16 + lr;
      const int k0 = c * 32 + lg * 8;
      const float* wp = W1 + row * 64 + k0;
      float4 a0 = *reinterpret_cast<const float4*>(wp);
      float4 a1 = *reinterpret_cast<const float4*>(wp + 4);
      bf16x8 f;
      f[0]=f2bf_s(a0.x); f[1]=f2bf_s(a0.y); f[2]=f2bf_s(a0.z); f[3]=f2bf_s(a0.w);
      f[4]=f2bf_s(a1.x); f[5]=f2bf_s(a1.y); f[6]=f2bf_s(a1.z); f[7]=f2bf_s(a1.w);
      wf[mt][c] = f;
    }

  for (int nt = 0; nt < 4; ++nt) {
    const int col = wv * 64 + nt * 16 + lr;      // LDS col (spatial, A row)
    bf16x8 xa[2];
#pragma unroll
    for (int c = 0; c < 2; ++c) {
      const int kc = c * 4 + lg;
      xa[c] = *reinterpret_cast<const bf16x8*>(
          lds + col * K1_STRIDE + ((kc + col) % K1_NKC) * 16);
    }
    f32x4 acc[6];
#pragma unroll
    for (int mt = 0; mt < 6; ++mt) acc[mt] = (f32x4){0.f, 0.f, 0.f, 0.f};
#pragma unroll
    for (int c = 0; c < 2; ++c)
#pragma unroll
      for (int mt = 0; mt < 6; ++mt)
        acc[mt] = __builtin_amdgcn_mfma_f32_16x16x32_bf16(xa[c], wf[mt][c], acc[mt], 0, 0, 0);
    const int nb = n0 + wv * 64 + nt * 16 + lg * 4;
#pragma unroll
    for (int mt = 0; mt < 6; ++mt) {
      const int o = mh * 96 + mt * 16 + lr;
      *reinterpret_cast<ushort4*>(y1 + (size_t)o * THW_ + nb) = pack4(acc[mt]);
    }
  }
}

// ================ K2: depthwise 3x3, 32x128 tile, conflict-free ================
// blockIdx.x = (o*T + t)*4 + strip ; strip covers 32 rows
__global__ __launch_bounds__(256) void k2_dw(
    const bf16* __restrict__ y1, const float* __restrict__ Wdw,
    bf16* __restrict__ y2) {
  __shared__ float tile[34][132];   // rows hs-1..hs+32, cols -1..128 (+pad)
  const int tid = threadIdx.x;
  const int blk = blockIdx.x;
  const int hs = (blk & 3) * 32;
  const int rest = blk >> 2;
  const int t = rest % T_;
  const int o = rest / T_;
  const bf16* src = y1 + ((size_t)o * T_ + t) * HW_;

  // zero halo columns (w = -1 and w = 128 are always pad)
  if (tid < 68) {
    const int r = tid >> 1, side = tid & 1;
    tile[r][side ? 129 : 0] = 0.f;
  }
  // main load: row r <-> hh = hs-1+r ; col 1+w <-> w
  {
    const int rr = tid >> 5, c4 = (tid & 31) * 4;
#pragma unroll
    for (int p = 0; p < 5; ++p) {
      const int r = p * 8 + rr;
      if (r < 34) {
        const int hh = hs - 1 + r;
        float e0 = 0.f, e1 = 0.f, e2 = 0.f, e3 = 0.f;
        if (hh >= 0 && hh < H_) {
          uint2 raw = *reinterpret_cast<const uint2*>(src + hh * W_ + c4);
          e0 = __uint_as_float(raw.x << 16);
          e1 = __uint_as_float(raw.x & 0xffff0000u);
          e2 = __uint_as_float(raw.y << 16);
          e3 = __uint_as_float(raw.y & 0xffff0000u);
        }
        tile[r][1 + c4]     = e0;
        tile[r][1 + c4 + 1] = e1;
        tile[r][1 + c4 + 2] = e2;
        tile[r][1 + c4 + 3] = e3;
      }
    }
  }
  __syncthreads();

  float kk[9];
#pragma unroll
  for (int i = 0; i < 9; ++i) kk[i] = Wdw[o * 9 + i];

  bf16* dst = y2 + ((size_t)o * T_ + t) * HW_;
  const int w = tid & 127;         // consecutive lanes -> consecutive cols
  const int r0 = (tid >> 7) * 16;  // 2 groups of 16 rows

  float a[3][3];
#pragma unroll
  for (int ky = 0; ky < 3; ++ky)
#pragma unroll
    for (int kx = 0; kx < 3; ++kx) a[ky][kx] = tile[r0 + ky][w + kx];

#pragma unroll
  for (int q = 0; q < 16; ++q) {
    float acc = 0.f;
#pragma unroll
    for (int ky = 0; ky < 3; ++ky)
#pragma unroll
      for (int kx = 0; kx < 3; ++kx)
        acc = fmaf(kk[ky * 3 + kx], a[ky][kx], acc);
    dst[(hs + r0 + q) * W_ + w] = __float2bfloat16(acc);
    if (q < 15) {
#pragma unroll
      for (int kx = 0; kx < 3; ++kx) {
        a[0][kx] = a[1][kx];
        a[1][kx] = a[2][kx];
        a[2][kx] = tile[r0 + q + 3][w + kx];
      }
    }
  }
}

// ================ K3 (MFMA, swapped): z = W_lin @ shuffled(y2) + b ================
#define K3_NKC 14
#define K3_STRIDE 224
__global__ __launch_bounds__(256) void k3_mfma(
    const bf16* __restrict__ y2, const float* __restrict__ W_lin,
    const float* __restrict__ b_lin, bf16* __restrict__ z) {
  __shared__ __align__(16) char lds[256 * K3_STRIDE];   // 56 KiB
  const int tid = threadIdx.x;
  const int s0 = blockIdx.x * 256;
  const int c2 = blockIdx.y;

  {
    const int cg = tid >> 3, dk = tid & 7;
    for (int it = 0; it < 10; ++it) {
      const int k = it * 8 + dk;
      const int c1 = (k * 205) >> 11;
      const int tt = k - c1 * 10;
      const bf16* src = y2 + ((size_t)((c1 * C2_ + c2) * T_ + tt)) * HW_ + s0 + cg * 8;
      uint4 raw = *reinterpret_cast<const uint4*>(src);
      const ushort* v = reinterpret_cast<const ushort*>(&raw);
      const int kc = k >> 3, ke = k & 7;
      int r = (kc + cg * 8) % K3_NKC;
#pragma unroll
      for (int j = 0; j < 8; ++j) {
        const int col = cg * 8 + j;
        *reinterpret_cast<ushort*>(lds + col * K3_STRIDE + r * 16 + ke * 2) = v[j];
        r = (r + 1 == K3_NKC) ? 0 : r + 1;
      }
    }
    const int col = tid;
    const uint4 zero4 = {0, 0, 0, 0};
    *reinterpret_cast<uint4*>(lds + col * K3_STRIDE + ((10 + col) % K3_NKC) * 16) = zero4;
    *reinterpret_cast<uint4*>(lds + col * K3_STRIDE + ((11 + col) % K3_NKC) * 16) = zero4;
  }
  __syncthreads();

  const int lane = tid & 63, wv = tid >> 6;
  const int lr = lane & 15, lg = lane >> 4;

  bf16x8 wf[5][3];
#pragma unroll
  for (int mt = 0; mt < 5; ++mt)
#pragma unroll
    for (int c = 0; c < 3; ++c) {
      const int row = mt * 16 + lr;
      const int k0 = c * 32 + lg * 8;
      bf16x8 f;
      if (k0 < 80) {
        const float* wp = W_lin + row * 80 + k0;
        float4 a0 = *reinterpret_cast<const float4*>(wp);
        float4 a1 = *reinterpret_cast<const float4*>(wp + 4);
        f[0]=f2bf_s(a0.x); f[1]=f2bf_s(a0.y); f[2]=f2bf_s(a0.z); f[3]=f2bf_s(a0.w);
        f[4]=f2bf_s(a1.x); f[5]=f2bf_s(a1.y); f[6]=f2bf_s(a1.z); f[7]=f2bf_s(a1.w);
      } else {
        f = (bf16x8){0,0,0,0,0,0,0,0};
      }
      wf[mt][c] = f;
    }
  float bias[5];
#pragma unroll
  for (int mt = 0; mt < 5; ++mt) bias[mt] = b_lin[mt * 16 + lr];

  for (int nt = 0; nt < 4; ++nt) {
    const int col = wv * 64 + nt * 16 + lr;
    bf16x8 xa[3];
#pragma unroll
    for (int c = 0; c < 3; ++c) {
      const int kc = c * 4 + lg;
      xa[c] = *reinterpret_cast<const bf16x8*>(
          lds + col * K3_STRIDE + ((kc + col) % K3_NKC) * 16);
    }
    f32x4 acc[5];
#pragma unroll
    for (int mt = 0; mt < 5; ++mt)
      acc[mt] = (f32x4){bias[mt], bias[mt], bias[mt], bias[mt]};
#pragma unroll
    for (int c = 0; c < 3; ++c)
#pragma unroll
      for (int mt = 0; mt < 5; ++mt)
        acc[mt] = __builtin_amdgcn_mfma_f32_16x16x32_bf16(xa[c], wf[mt][c], acc[mt], 0, 0, 0);
    const int sb = s0 + wv * 64 + nt * 16 + lg * 4;
#pragma unroll
    for (int mt = 0; mt < 5; ++mt) {
      const int u = c2 * TG_ + mt * 16 + lr;
      *reinterpret_cast<ushort4*>(z + (size_t)u * HW_ + sb) = pack4(acc[mt]);
    }
  }
}

// ================ K4: sum of squares for q,k rows — unchanged ================
__global__ __launch_bounds__(256) void k4_ssq(
    const bf16* __restrict__ z, float* __restrict__ ssq) {
  __shared__ float red[256];
  int u = blockIdx.x;
  const bf16* p = z + (size_t)u * HW_;
  float acc = 0.f;
  for (int it = 0; it < 8; ++it) {
    int s = it * 2048 + threadIdx.x * 8;
    uint4 raw = *reinterpret_cast<const uint4*>(p + s);
    float f[8]; unpack8(raw, f);
#pragma unroll
    for (int e = 0; e < 8; ++e) acc = fmaf(f[e], f[e], acc);
  }
  red[threadIdx.x] = acc;
  __syncthreads();
  for (int st = 128; st > 0; st >>= 1) {
    if (threadIdx.x < st) red[threadIdx.x] += red[threadIdx.x + st];
    __syncthreads();
  }
  if (threadIdx.x == 0) ssq[u] = red[0];
}

// ================ K5 (MFMA): Gpart[chunk] = partial QK^T over 512-s chunk ================
__global__ __launch_bounds__(256) void k5_mfma(
    const bf16* __restrict__ z, float* __restrict__ Gpart) {
  __shared__ __align__(16) float gbuf[2][TG_ * TG_];   // 51.2 KiB
  const int chunk = blockIdx.x, h = blockIdx.y;
  const int tid = threadIdx.x;
  const int lane = tid & 63, wv = tid >> 6;
  const int lr = lane & 15, lg = lane >> 4;

  const bf16* qbase = z + (size_t)(h * TG_) * HW_;
  const bf16* kbase = z + (size_t)((8 + h) * TG_) * HW_;

  f32x4 acc[5][5];
#pragma unroll
  for (int a = 0; a < 5; ++a)
#pragma unroll
    for (int b2 = 0; b2 < 5; ++b2) acc[a][b2] = (f32x4){0.f, 0.f, 0.f, 0.f};

  const int s0 = chunk * 512 + wv * 128;
  for (int s = s0; s < s0 + 128; s += 32) {
    bf16x8 qa[5], kb[5];
#pragma unroll
    for (int a = 0; a < 5; ++a)
      qa[a] = *reinterpret_cast<const bf16x8*>(qbase + (size_t)(a * 16 + lr) * HW_ + s + lg * 8);
#pragma unroll
    for (int a = 0; a < 5; ++a)
      kb[a] = *reinterpret_cast<const bf16x8*>(kbase + (size_t)(a * 16 + lr) * HW_ + s + lg * 8);
#pragma unroll
    for (int a = 0; a < 5; ++a)
#pragma unroll
      for (int b2 = 0; b2 < 5; ++b2)
        acc[a][b2] = __builtin_amdgcn_mfma_f32_16x16x32_bf16(qa[a], kb[b2], acc[a][b2], 0, 0, 0);
  }

  if (wv == 1 || wv == 3) {
    float* dst = gbuf[wv >> 1];
#pragma unroll
    for (int a = 0; a < 5; ++a)
#pragma unroll
      for (int b2 = 0; b2 < 5; ++b2)
#pragma unroll
        for (int j = 0; j < 4; ++j)
          dst[(a * 16 + lg * 4 + j) * TG_ + b2 * 16 + lr] = acc[a][b2][j];
  }
  __syncthreads();
  if (wv == 0 || wv == 2) {
    const float* srcb = gbuf[wv >> 1];
#pragma unroll
    for (int a = 0; a < 5; ++a)
#pragma unroll
      for (int b2 = 0; b2 < 5; ++b2)
#pragma unroll
        for (int j = 0; j < 4; ++j)
          acc[a][b2][j] += srcb[(a * 16 + lg * 4 + j) * TG_ + b2 * 16 + lr];
  }
  __syncthreads();
  if (wv == 2) {
#pragma unroll
    for (int a = 0; a < 5; ++a)
#pragma unroll
      for (int b2 = 0; b2 < 5; ++b2)
#pragma unroll
        for (int j = 0; j < 4; ++j)
          gbuf[0][(a * 16 + lg * 4 + j) * TG_ + b2 * 16 + lr] = acc[a][b2][j];
  }
  __syncthreads();
  if (wv == 0) {
    float* gp = Gpart + ((size_t)chunk * 8 + h) * TG_ * TG_;
#pragma unroll
    for (int a = 0; a < 5; ++a)
#pragma unroll
      for (int b2 = 0; b2 < 5; ++b2)
#pragma unroll
        for (int j = 0; j < 4; ++j) {
          const int i = a * 16 + lg * 4 + j, jj = b2 * 16 + lr;
          gp[i * TG_ + jj] = acc[a][b2][j] + gbuf[0][i * TG_ + jj];
        }
  }
}

// ================ K6: softmax — unchanged ================
__global__ __launch_bounds__(128) void k6_softmax(
    const float* __restrict__ Gpart, const float* __restrict__ ssq,
    const float* __restrict__ temp, float* __restrict__ attn) {
  __shared__ float red[128];
  __shared__ float smax, ssum;
  int h = blockIdx.x / TG_, i = blockIdx.x % TG_;
  int j = threadIdx.x;
  float logit = -1e30f;
  if (j < TG_) {
    float g = 0.f;
    for (int c = 0; c < 32; ++c)
      g += Gpart[(((size_t)c * 8 + h) * TG_ + i) * TG_ + j];
    float nq = ssq[h * TG_ + i];
    float nk = ssq[(8 + h) * TG_ + j];
    float sq = 1.f / fmaxf(sqrtf(nq), 1e-12f);
    float sk = 1.f / fmaxf(sqrtf(nk), 1e-12f);
    logit = g * sq * sk * temp[h];
  }
  red[j] = logit;
  __syncthreads();
  if (j == 0) {
    float m = -1e30f;
    for (int x2 = 0; x2 < TG_; ++x2) m = fmaxf(m, red[x2]);
    smax = m;
  }
  __syncthreads();
  float e = (j < TG_) ? expf(logit - smax) : 0.f;
  red[j] = e;
  __syncthreads();
  if (j == 0) {
    float s = 0.f;
    for (int x2 = 0; x2 < TG_; ++x2) s += red[x2];
    ssum = s;
  }
  __syncthreads();
  if (j < TG_) attn[((size_t)h * TG_ + i) * TG_ + j] = e / ssum;
}

// ================ K7a (MFMA, swapped): att_out = attn @ v ================
__global__ __launch_bounds__(256) void k7a_mfma(
    const bf16* __restrict__ z, const float* __restrict__ attn,
    bf16* __restrict__ att_out) {
  __shared__ __align__(16) char lds[256 * K3_STRIDE];   // 56 KiB
  const int tid = threadIdx.x;
  const int s0 = blockIdx.x * 256;
  const int h = blockIdx.y;
  const int voff = (16 + h) * TG_;

  {
    const int cg = tid >> 3, dk = tid & 7;
    for (int it = 0; it < 10; ++it) {
      const int k = it * 8 + dk;
      const bf16* src = z + (size_t)(voff + k) * HW_ + s0 + cg * 8;
      uint4 raw = *reinterpret_cast<const uint4*>(src);
      const ushort* v = reinterpret_cast<const ushort*>(&raw);
      const int kc = k >> 3, ke = k & 7;
      int r = (kc + cg * 8) % K3_NKC;
#pragma unroll
      for (int j = 0; j < 8; ++j) {
        const int col = cg * 8 + j;
        *reinterpret_cast<ushort*>(lds + col * K3_STRIDE + r * 16 + ke * 2) = v[j];
        r = (r + 1 == K3_NKC) ? 0 : r + 1;
      }
    }
    const int col = tid;
    const uint4 zero4 = {0, 0, 0, 0};
    *reinterpret_cast<uint4*>(lds + col * K3_STRIDE + ((10 + col) % K3_NKC) * 16) = zero4;
    *reinterpret_cast<uint4*>(lds + col * K3_STRIDE + ((11 + col) % K3_NKC) * 16) = zero4;
  }
  __syncthreads();

  const int lane = tid & 63, wv = tid >> 6;
  const int lr = lane & 15, lg = lane >> 4;

  bf16x8 wf[5][3];
#pragma unroll
  for (int mt = 0; mt < 5; ++mt)
#pragma unroll
    for (int c = 0; c < 3; ++c) {
      const int row = mt * 16 + lr;
      const int k0 = c * 32 + lg * 8;
      bf16x8 f;
      if (k0 < 80) {
        const float* ap = attn + ((size_t)h * TG_ + row) * TG_ + k0;
        float4 a0 = *reinterpret_cast<const float4*>(ap);
        float4 a1 = *reinterpret_cast<const float4*>(ap + 4);
        f[0]=f2bf_s(a0.x); f[1]=f2bf_s(a0.y); f[2]=f2bf_s(a0.z); f[3]=f2bf_s(a0.w);
        f[4]=f2bf_s(a1.x); f[5]=f2bf_s(a1.y); f[6]=f2bf_s(a1.z); f[7]=f2bf_s(a1.w);
      } else {
        f = (bf16x8){0,0,0,0,0,0,0,0};
      }
      wf[mt][c] = f;
    }

  for (int nt = 0; nt < 4; ++nt) {
    const int col = wv * 64 + nt * 16 + lr;
    bf16x8 xa[3];
#pragma unroll
    for (int c = 0; c < 3; ++c) {
      const int kc = c * 4 + lg;
      xa[c] = *reinterpret_cast<const bf16x8*>(
          lds + col * K3_STRIDE + ((kc + col) % K3_NKC) * 16);
    }
    f32x4 acc[5];
#pragma unroll
    for (int mt = 0; mt < 5; ++mt) acc[mt] = (f32x4){0.f, 0.f, 0.f, 0.f};
#pragma unroll
    for (int c = 0; c < 3; ++c)
#pragma unroll
      for (int mt = 0; mt < 5; ++mt)
        acc[mt] = __builtin_amdgcn_mfma_f32_16x16x32_bf16(xa[c], wf[mt][c], acc[mt], 0, 0, 0);
    const int sb = s0 + wv * 64 + nt * 16 + lg * 4;
#pragma unroll
    for (int mt = 0; mt < 5; ++mt) {
      const int u = h * TG_ + mt * 16 + lr;
      *reinterpret_cast<ushort4*>(att_out + (size_t)u * HW_ + sb) = pack4(acc[mt]);
    }
  }
}

// ================ K7b (MFMA, swapped): out = W_out @ regroup(att_out), f32 out ================
__global__ __launch_bounds__(256) void k7b_mfma(
    const bf16* __restrict__ att_out, const float* __restrict__ W_out,
    float* __restrict__ out) {
  __shared__ __align__(16) char lds[256 * K1_STRIDE];   // 40 KiB
  const int tid = threadIdx.x;
  const int n0 = blockIdx.x * 256;
  const int t = n0 >> 14;
  const int sb0 = n0 & (HW_ - 1);

  {
    const int cg = tid >> 3, dk = tid & 7;
    for (int it = 0; it < 8; ++it) {
      const int k = it * 8 + dk;
      const int row = (k >> 3) * TG_ + (k & 7) * T_ + t;
      const bf16* src = att_out + (size_t)row * HW_ + sb0 + cg * 8;
      uint4 raw = *reinterpret_cast<const uint4*>(src);
      const ushort* v = reinterpret_cast<const ushort*>(&raw);
      int r = (it + cg * 8) % K1_NKC;
#pragma unroll
      for (int j = 0; j < 8; ++j) {
        const int col = cg * 8 + j;
        *reinterpret_cast<ushort*>(lds + col * K1_STRIDE + r * 16 + dk * 2) = v[j];
        r = (r + 1 == K1_NKC) ? 0 : r + 1;
      }
    }
  }
  __syncthreads();

  const int lane = tid & 63, wv = tid >> 6;
  const int lr = lane & 15, lg = lane >> 4;

  bf16x8 wf[4][2];
#pragma unroll
  for (int mt = 0; mt < 4; ++mt)
#pragma unroll
    for (int c = 0; c < 2; ++c) {
      const int row = mt * 16 + lr;
      const int k0 = c * 32 + lg * 8;
      const float* wp = W_out + row * 64 + k0;
      float4 a0 = *reinterpret_cast<const float4*>(wp);
      float4 a1 = *reinterpret_cast<const float4*>(wp + 4);
      bf16x8 f;
      f[0]=f2bf_s(a0.x); f[1]=f2bf_s(a0.y); f[2]=f2bf_s(a0.z); f[3]=f2bf_s(a0.w);
      f[4]=f2bf_s(a1.x); f[5]=f2bf_s(a1.y); f[6]=f2bf_s(a1.z); f[7]=f2bf_s(a1.w);
      wf[mt][c] = f;
    }

  for (int nt = 0; nt < 4; ++nt) {
    const int col = wv * 64 + nt * 16 + lr;
    bf16x8 xa[2];
#pragma unroll
    for (int c = 0; c < 2; ++c) {
      const int kc = c * 4 + lg;
      xa[c] = *reinterpret_cast<const bf16x8*>(
          lds + col * K1_STRIDE + ((kc + col) % K1_NKC) * 16);
    }
    f32x4 acc[4];
#pragma unroll
    for (int mt = 0; mt < 4; ++mt) acc[mt] = (f32x4){0.f, 0.f, 0.f, 0.f};
#pragma unroll
    for (int c = 0; c < 2; ++c)
#pragma unroll
      for (int mt = 0; mt < 4; ++mt)
        acc[mt] = __builtin_amdgcn_mfma_f32_16x16x32_bf16(xa[c], wf[mt][c], acc[mt], 0, 0, 0);
    const int nb = n0 + wv * 64 + nt * 16 + lg * 4;
#pragma unroll
    for (int mt = 0; mt < 4; ++mt) {
      const int o = mt * 16 + lr;
      *reinterpret_cast<float4*>(out + (size_t)o * THW_ + nb) =
          (float4){acc[mt][0], acc[mt][1], acc[mt][2], acc[mt][3]};
    }
  }
}

extern "C" void kernel_launch(void* const* d_in, const int* in_sizes, int n_in,
                              void* d_out, int out_size, void* d_ws, size_t ws_size,
                              hipStream_t stream) {
  const float* x    = (const float*)d_in[0];
  const float* W1   = (const float*)d_in[1];
  const float* Wdw  = (const float*)d_in[2];
  const float* Wlin = (const float*)d_in[3];
  const float* blin = (const float*)d_in[4];
  const float* temp = (const float*)d_in[5];
  const float* Wout = (const float*)d_in[6];
  float* out = (float*)d_out;

  const size_t SLOT = (size_t)C3_ * THW_ * 2;   // 62,914,560 bytes
  char* ws = (char*)d_ws;
  bf16* slotA = (bf16*)ws;
  char* slotB = ws + SLOT;

  bf16* y1 = slotA;
  bf16* y2 = (bf16*)slotB;
  bf16* z  = slotA;
  float* Gpart   = (float*)slotB;                // 6,553,600 B
  float* attn    = (float*)(slotB + 6553600);    //   204,800 B
  float* ssq     = (float*)(slotB + 6758400);    //     5,120 B
  bf16*  att_out = (bf16*)(slotB + 6763520);     // 20,971,520 B

  for (int b = 0; b < 2; ++b) {
    const float* x_b = x + (size_t)b * C_ * THW_;
    float* out_b = out + (size_t)b * C_ * THW_;

    k1_mfma<<<dim3(THW_ / 256, 2), 256, 0, stream>>>(x_b, W1, y1);
    k2_dw<<<C3_ * T_ * 4, 256, 0, stream>>>(y1, Wdw, y2);
    k3_mfma<<<dim3(HW_ / 256, C2_), 256, 0, stream>>>(y2, Wlin, blin, z);
    k4_ssq<<<1280, 256, 0, stream>>>(z, ssq);
    k5_mfma<<<dim3(32, NH_), 256, 0, stream>>>(z, Gpart);
    k6_softmax<<<8 * TG_, 128, 0, stream>>>(Gpart, ssq, temp, attn);
    k7a_mfma<<<dim3(HW_ / 256, NH_), 256, 0, stream>>>(z, attn, att_out);
    k7b_mfma<<<THW_ / 256, 256, 0, stream>>>(att_out, Wout, out_b);
  }
}